// Round 5
// baseline (197.984 us; speedup 1.0000x reference)
//
#include <hip/hip_runtime.h>

// Problem constants (match reference file)
constexpr int Dv = 160, Hv = 192, Wv = 160;
constexpr int NN = Dv * Hv * Wv;  // 4,915,200 voxels

// Pure cached-gather structure (round 5): NO LDS, NO barrier.
// Rounds 0-4 showed the stage->barrier->compute structure leaves the CU
// idle most of the time (VALU+LDS+TA cycle sums ~half of wall cycles, all
// waves drain vmcnt in lockstep generations). Here every corner fetch is a
// direct global load served by L1/L2 (block working set ~27KB; src is
// 20MB = L3-resident, so HBM sees it once), reads are issued throughout
// the kernel lifetime, and stores interleave per k-group.
// Thread layout: 8 x-groups (4 consecutive voxels) x 8 y x 4 z (2 slices)
// -> flow2 reads and out writes are 16B/lane dwordx4 (Guideline 13).
constexpr int TW = 32, TH = 8, TD = 8;   // grid 5 x 24 x 20 = 2400 blocks

// Trilinear sample of 3-channel flow1 at quirk-unnormalized coords:
// in-bounds only near the (0,0,0) corner (all three axes must be ~0), so
// this is execz-skipped for essentially every wave.
__device__ __forceinline__ void tri3_rare(const float* __restrict__ v,
                                          float gx, float gy, float gz,
                                          float& o0, float& o1, float& o2) {
  o0 = 0.0f; o1 = 0.0f; o2 = 0.0f;
  float ix = ((gx + 1.0f) * (float)Wv - 1.0f) * 0.5f;
  float iy = ((gy + 1.0f) * (float)Hv - 1.0f) * 0.5f;
  float iz = ((gz + 1.0f) * (float)Dv - 1.0f) * 0.5f;
  float fx = floorf(ix), fy = floorf(iy), fz = floorf(iz);
  int x0 = (int)fx, y0 = (int)fy, z0 = (int)fz;
  if (x0 < -1 || x0 >= Wv || y0 < -1 || y0 >= Hv || z0 < -1 || z0 >= Dv)
    return;  // entire 2x2x2 support OOB -> zeros
  float wx = ix - fx, wy = iy - fy, wz = iz - fz;
#pragma unroll
  for (int c = 0; c < 8; ++c) {
    const int dz = (c >> 2) & 1, dy = (c >> 1) & 1, dx = c & 1;
    int zi = z0 + dz, yi = y0 + dy, xi = x0 + dx;
    if ((unsigned)zi < (unsigned)Dv && (unsigned)yi < (unsigned)Hv &&
        (unsigned)xi < (unsigned)Wv) {
      float wgt = (dz ? wz : 1.0f - wz) * (dy ? wy : 1.0f - wy) *
                  (dx ? wx : 1.0f - wx);
      int lin = (zi * Hv + yi) * Wv + xi;
      o0 += wgt * v[lin];
      o1 += wgt * v[NN + lin];
      o2 += wgt * v[2 * NN + lin];
    }
  }
}

__global__ __launch_bounds__(256)
void st_gather_kernel(const float* __restrict__ src,
                      const float* __restrict__ flow1,
                      const float* __restrict__ flow2,
                      const float* __restrict__ rfp,
                      float* __restrict__ out) {
  const int tid = threadIdx.x;
  const int bx0 = blockIdx.x * TW;   // w origin
  const int by0 = blockIdx.y * TH;   // h origin
  const int bz0 = blockIdx.z * TD;   // d origin
  const float rf = rfp[0];

  const int lx = tid & 7;            // x-group: 4 consecutive voxels
  const int ly = (tid >> 3) & 7;     // 0..7
  const int lz = tid >> 6;           // 0..3, handles z-slices 2*lz, 2*lz+1
  const int w0 = bx0 + lx * 4;
  const int h = by0 + ly;

  // ---- vectorized flow2 prefetch for both owned z-slices (6 x dwordx4) ----
  float4 f2d4[2], f2h4[2], f2w4[2];
#pragma unroll
  for (int s = 0; s < 2; ++s) {
    int d = bz0 + 2 * lz + s;
    int idx = (d * Hv + h) * Wv + w0;   // x multiple of 4 -> 16B aligned
    f2d4[s] = *(const float4*)(flow2 + idx);
    f2h4[s] = *(const float4*)(flow2 + NN + idx);
    f2w4[s] = *(const float4*)(flow2 + 2 * NN + idx);
  }

  const float hf = (float)h;
  constexpr float KX = (float)Wv / (float)(Wv - 1);
  constexpr float KY = (float)Hv / (float)(Hv - 1);
  constexpr float KZ = (float)Dv / (float)(Dv - 1);

#pragma unroll
  for (int s = 0; s < 2; ++s) {
    const int d = bz0 + 2 * lz + s;
    const float df = (float)d;
    const int idx = (d * Hv + h) * Wv + w0;

    float4 def, ofd4, ofh4, ofw4;
#pragma unroll
    for (int j = 0; j < 4; ++j) {
      const float wf = (float)(w0 + j);
      const float f2dv = (&f2d4[s].x)[j];
      const float f2hv = (&f2h4[s].x)[j];
      const float f2wv = (&f2w4[s].x)[j];

      // grid2 (x,y,z) = (w + rf*f2w, h + rf*f2h, d + rf*f2d) [NOT normalized]
      float a0, a1, a2;  // flow1 warped (d,h,w channels)
      tri3_rare(flow1, wf + rf * f2wv, hf + rf * f2hv, df + rf * f2dv,
                a0, a1, a2);

      float of_d = a0 + f2dv;
      float of_h = a1 + f2hv;
      float of_w = a2 + f2wv;
      (&ofd4.x)[j] = of_d;
      (&ofh4.x)[j] = of_h;
      (&ofw4.x)[j] = of_w;

      // src sample coords (algebraically simplified, align_corners=False):
      // ix = (w + rf*of_w) * W/(W-1) - 0.5, etc.
      float ix = (wf + rf * of_w) * KX - 0.5f;
      float iy = (hf + rf * of_h) * KY - 0.5f;
      float iz = (df + rf * of_d) * KZ - 0.5f;

      float fx = floorf(ix), fy = floorf(iy), fz = floorf(iz);
      float wx = ix - fx, wy = iy - fy, wz = iz - fz;
      int x0 = (int)fx, y0 = (int)fy, z0 = (int)fz;

      // zeros-padding validity -> per-axis weights (clamp + zero weight)
      float wx0 = ((unsigned)x0 < (unsigned)Wv) ? (1.0f - wx) : 0.0f;
      float wx1 = ((unsigned)(x0 + 1) < (unsigned)Wv) ? wx : 0.0f;
      float wy0 = ((unsigned)y0 < (unsigned)Hv) ? (1.0f - wy) : 0.0f;
      float wy1 = ((unsigned)(y0 + 1) < (unsigned)Hv) ? wy : 0.0f;
      float wz0 = ((unsigned)z0 < (unsigned)Dv) ? (1.0f - wz) : 0.0f;
      float wz1 = ((unsigned)(z0 + 1) < (unsigned)Dv) ? wz : 0.0f;

      int xa0 = min(max(x0, 0), Wv - 1), xa1 = min(max(x0 + 1, 0), Wv - 1);
      int ya0 = min(max(y0, 0), Hv - 1), ya1 = min(max(y0 + 1, 0), Hv - 1);
      int za0 = min(max(z0, 0), Dv - 1), za1 = min(max(z0 + 1, 0), Dv - 1);

      // direct L1/L2-served corner gather (uniform path, no divergence)
      int r00 = (za0 * Hv + ya0) * Wv;
      int r01 = (za0 * Hv + ya1) * Wv;
      int r10 = (za1 * Hv + ya0) * Wv;
      int r11 = (za1 * Hv + ya1) * Wv;
      float v000 = src[r00 + xa0], v001 = src[r00 + xa1];
      float v010 = src[r01 + xa0], v011 = src[r01 + xa1];
      float v100 = src[r10 + xa0], v101 = src[r10 + xa1];
      float v110 = src[r11 + xa0], v111 = src[r11 + xa1];

      float c00 = v000 * wx0 + v001 * wx1;
      float c01 = v010 * wx0 + v011 * wx1;
      float c10 = v100 * wx0 + v101 * wx1;
      float c11 = v110 * wx0 + v111 * wx1;
      float c0 = c00 * wy0 + c01 * wy1;
      float c1 = c10 * wy0 + c11 * wy1;
      (&def.x)[j] = c0 * wz0 + c1 * wz1;
    }

    // ---- vectorized stores: 4 x dwordx4 per slice ----
    *(float4*)(out + idx) = def;
    *(float4*)(out + NN + idx) = ofd4;
    *(float4*)(out + 2 * NN + idx) = ofh4;
    *(float4*)(out + 3 * NN + idx) = ofw4;
  }
}

extern "C" void kernel_launch(void* const* d_in, const int* in_sizes, int n_in,
                              void* d_out, int out_size, void* d_ws, size_t ws_size,
                              hipStream_t stream) {
  const float* src   = (const float*)d_in[0];
  const float* flow1 = (const float*)d_in[1];
  const float* flow2 = (const float*)d_in[2];
  const float* rfp   = (const float*)d_in[3];
  float* out = (float*)d_out;

  dim3 grid(Wv / TW, Hv / TH, Dv / TD);  // 5 x 24 x 20
  hipLaunchKernelGGL(st_gather_kernel, grid, dim3(256), 0, stream,
                     src, flow1, flow2, rfp, out);
}

// Round 6
// 178.325 us; speedup vs baseline: 1.1102x; 1.1102x over previous
//
#include <hip/hip_runtime.h>

// Problem constants (match reference file)
constexpr int Dv = 160, Hv = 192, Wv = 160;
constexpr int NN = Dv * Hv * Wv;  // 4,915,200 voxels

// Round 6: same structure as the best kernel (R3: LDS tile + vectorized IO)
// but FINER GRAIN: 4 voxels/thread, 4800 blocks = 19200 waves = 2.34
// machine-fulls (vs 1.17). Rounds 0-5 showed every pipe <30% busy and
// occupancy capped at ~33% because the grid itself was ~1 machine-full:
// duration tracked grid size (960 blk -> 60us, 2400 blk -> 50us), not
// bytes, not LDS, not residency caps.
// Thread layout: 8 x-groups (4 consecutive voxels) x 8 y x 4 z-slices.
constexpr int TW = 32, TH = 8, TD = 4;   // grid 5 x 24 x 40 = 4800 blocks
// LDS support tile: x halo [-4,+4) (SX=40, 16B-aligned segments),
// y halo [-2,+4) (SY=13), z halo [-2,+4) (SZ=9).
constexpr int SX = 40, SY = 13, SZ = 9;
constexpr int SLEN = SX * SY * SZ;            // 4680 floats
constexpr int SVEC = SLEN / 4;                // 1170 16B segments
constexpr int SITER = (SVEC + 255) / 256;     // 5 staging iterations
constexpr int SPAD = SITER * 256 * 4;         // 5120 floats = 20.5 KB -> 7 blk/CU

// Trilinear sample of 3-channel flow1 at quirk-unnormalized coords:
// in-bounds only near the (0,0,0) corner, so this is execz-skipped for
// essentially every wave.
__device__ __forceinline__ void tri3_rare(const float* __restrict__ v,
                                          float gx, float gy, float gz,
                                          float& o0, float& o1, float& o2) {
  o0 = 0.0f; o1 = 0.0f; o2 = 0.0f;
  float ix = ((gx + 1.0f) * (float)Wv - 1.0f) * 0.5f;
  float iy = ((gy + 1.0f) * (float)Hv - 1.0f) * 0.5f;
  float iz = ((gz + 1.0f) * (float)Dv - 1.0f) * 0.5f;
  float fx = floorf(ix), fy = floorf(iy), fz = floorf(iz);
  int x0 = (int)fx, y0 = (int)fy, z0 = (int)fz;
  if (x0 < -1 || x0 >= Wv || y0 < -1 || y0 >= Hv || z0 < -1 || z0 >= Dv)
    return;  // entire 2x2x2 support OOB -> zeros
  float wx = ix - fx, wy = iy - fy, wz = iz - fz;
#pragma unroll
  for (int c = 0; c < 8; ++c) {
    const int dz = (c >> 2) & 1, dy = (c >> 1) & 1, dx = c & 1;
    int zi = z0 + dz, yi = y0 + dy, xi = x0 + dx;
    if ((unsigned)zi < (unsigned)Dv && (unsigned)yi < (unsigned)Hv &&
        (unsigned)xi < (unsigned)Wv) {
      float wgt = (dz ? wz : 1.0f - wz) * (dy ? wy : 1.0f - wy) *
                  (dx ? wx : 1.0f - wx);
      int lin = (zi * Hv + yi) * Wv + xi;
      o0 += wgt * v[lin];
      o1 += wgt * v[NN + lin];
      o2 += wgt * v[2 * NN + lin];
    }
  }
}

__global__ __launch_bounds__(256)
void st_fine_kernel(const float* __restrict__ src,
                    const float* __restrict__ flow1,
                    const float* __restrict__ flow2,
                    const float* __restrict__ rfp,
                    float* __restrict__ out) {
  __shared__ float tile[SPAD];

  const int tid = threadIdx.x;
  const int bx0 = blockIdx.x * TW;   // w origin
  const int by0 = blockIdx.y * TH;   // h origin
  const int bz0 = blockIdx.z * TD;   // d origin
  const float rf = rfp[0];

  const int lx = tid & 7;            // x-group: 4 consecutive voxels
  const int ly = (tid >> 3) & 7;     // 0..7
  const int lz = tid >> 6;           // 0..3: one z-slice per thread
  const int w0 = bx0 + lx * 4;
  const int h = by0 + ly;
  const int d = bz0 + lz;
  const int idx = (d * Hv + h) * Wv + w0;   // 16B-aligned

  // ---- vectorized flow2 prefetch (3 x dwordx4) ----
  float4 f2d4 = *(const float4*)(flow2 + idx);
  float4 f2h4 = *(const float4*)(flow2 + NN + idx);
  float4 f2w4 = *(const float4*)(flow2 + 2 * NN + idx);

  // ---- async global->LDS stage (16B wide, 5 iterations) ----
  // LDS dest is linear (HW: wave-uniform base + lane*16); the 4-aligned
  // x-halo guarantees each 16B segment is fully-in or fully-out of the
  // x-range, so the segment-start clamp is exact for live cells and
  // finite-garbage (weight-zeroed) for halo cells.
  const int bxo = bx0 - 4, byo = by0 - 2, bzo = bz0 - 2;
#pragma unroll
  for (int i = 0; i < SITER; ++i) {
    int t = tid + i * 256;
    int tt = (i == SITER - 1) ? min(t, SVEC - 1) : t;
    int e = tt * 4;                     // element offset, multiple of 4
    int tz = e / (SY * SX);
    int r = e - tz * (SY * SX);
    int ty = r / SX;
    int tx = r - ty * SX;               // multiple of 4
    int gx = min(max(bxo + tx, 0), Wv - 4);
    int gy = min(max(byo + ty, 0), Hv - 1);
    int gz = min(max(bzo + tz, 0), Dv - 1);
    int g = (gz * Hv + gy) * Wv + gx;   // 16B-aligned
    __builtin_amdgcn_global_load_lds(
        (const __attribute__((address_space(1))) void*)(src + g),
        (__attribute__((address_space(3))) void*)(tile + e), 16, 0, 0);
  }
  __syncthreads();  // drains vmcnt for the LDS stage

  const float hf = (float)h, df = (float)d;
  constexpr float KX = (float)Wv / (float)(Wv - 1);
  constexpr float KY = (float)Hv / (float)(Hv - 1);
  constexpr float KZ = (float)Dv / (float)(Dv - 1);

  float4 def, ofd4, ofh4, ofw4;
#pragma unroll
  for (int j = 0; j < 4; ++j) {
    const float wf = (float)(w0 + j);
    const float f2dv = (&f2d4.x)[j];
    const float f2hv = (&f2h4.x)[j];
    const float f2wv = (&f2w4.x)[j];

    // grid2 (x,y,z) = (w + rf*f2w, h + rf*f2h, d + rf*f2d) [NOT normalized]
    float a0, a1, a2;  // flow1 warped (d,h,w channels)
    tri3_rare(flow1, wf + rf * f2wv, hf + rf * f2hv, df + rf * f2dv,
              a0, a1, a2);

    float of_d = a0 + f2dv;
    float of_h = a1 + f2hv;
    float of_w = a2 + f2wv;
    (&ofd4.x)[j] = of_d;
    (&ofh4.x)[j] = of_h;
    (&ofw4.x)[j] = of_w;

    // src sample coords (algebraically simplified, align_corners=False):
    // ix = (w + rf*of_w) * W/(W-1) - 0.5, etc.
    float ix = (wf + rf * of_w) * KX - 0.5f;
    float iy = (hf + rf * of_h) * KY - 0.5f;
    float iz = (df + rf * of_d) * KZ - 0.5f;

    float fx = floorf(ix), fy = floorf(iy), fz = floorf(iz);
    float wx = ix - fx, wy = iy - fy, wz = iz - fz;
    int x0 = (int)fx, y0 = (int)fy, z0 = (int)fz;

    // zeros-padding validity -> per-axis weights
    float wx0 = ((unsigned)x0 < (unsigned)Wv) ? (1.0f - wx) : 0.0f;
    float wx1 = ((unsigned)(x0 + 1) < (unsigned)Wv) ? wx : 0.0f;
    float wy0 = ((unsigned)y0 < (unsigned)Hv) ? (1.0f - wy) : 0.0f;
    float wy1 = ((unsigned)(y0 + 1) < (unsigned)Hv) ? wy : 0.0f;
    float wz0 = ((unsigned)z0 < (unsigned)Dv) ? (1.0f - wz) : 0.0f;
    float wz1 = ((unsigned)(z0 + 1) < (unsigned)Dv) ? wz : 0.0f;

    int txi = x0 - bxo, tyi = y0 - byo, tzi = z0 - bzo;
    bool fast = ((unsigned)txi <= (unsigned)(SX - 2)) &
                ((unsigned)tyi <= (unsigned)(SY - 2)) &
                ((unsigned)tzi <= (unsigned)(SZ - 2));

    float v000, v001, v010, v011, v100, v101, v110, v111;
    if (fast) {
      int base = (tzi * SY + tyi) * SX + txi;
      v000 = tile[base];
      v001 = tile[base + 1];
      v010 = tile[base + SX];
      v011 = tile[base + SX + 1];
      v100 = tile[base + SY * SX];
      v101 = tile[base + SY * SX + 1];
      v110 = tile[base + SY * SX + SX];
      v111 = tile[base + SY * SX + SX + 1];
    } else {
      // rare (~1e-6/voxel): out-of-tile -> clamped global gather
      int xa0 = min(max(x0, 0), Wv - 1), xa1 = min(max(x0 + 1, 0), Wv - 1);
      int ya0 = min(max(y0, 0), Hv - 1), ya1 = min(max(y0 + 1, 0), Hv - 1);
      int za0 = min(max(z0, 0), Dv - 1), za1 = min(max(z0 + 1, 0), Dv - 1);
      int r00 = (za0 * Hv + ya0) * Wv;
      int r01 = (za0 * Hv + ya1) * Wv;
      int r10 = (za1 * Hv + ya0) * Wv;
      int r11 = (za1 * Hv + ya1) * Wv;
      v000 = src[r00 + xa0]; v001 = src[r00 + xa1];
      v010 = src[r01 + xa0]; v011 = src[r01 + xa1];
      v100 = src[r10 + xa0]; v101 = src[r10 + xa1];
      v110 = src[r11 + xa0]; v111 = src[r11 + xa1];
    }

    float c00 = v000 * wx0 + v001 * wx1;
    float c01 = v010 * wx0 + v011 * wx1;
    float c10 = v100 * wx0 + v101 * wx1;
    float c11 = v110 * wx0 + v111 * wx1;
    float c0 = c00 * wy0 + c01 * wy1;
    float c1 = c10 * wy0 + c11 * wy1;
    (&def.x)[j] = c0 * wz0 + c1 * wz1;
  }

  // ---- vectorized stores: 4 x dwordx4 ----
  *(float4*)(out + idx) = def;
  *(float4*)(out + NN + idx) = ofd4;
  *(float4*)(out + 2 * NN + idx) = ofh4;
  *(float4*)(out + 3 * NN + idx) = ofw4;
}

extern "C" void kernel_launch(void* const* d_in, const int* in_sizes, int n_in,
                              void* d_out, int out_size, void* d_ws, size_t ws_size,
                              hipStream_t stream) {
  const float* src   = (const float*)d_in[0];
  const float* flow1 = (const float*)d_in[1];
  const float* flow2 = (const float*)d_in[2];
  const float* rfp   = (const float*)d_in[3];
  float* out = (float*)d_out;

  dim3 grid(Wv / TW, Hv / TH, Dv / TD);  // 5 x 24 x 40 = 4800 blocks
  hipLaunchKernelGGL(st_fine_kernel, grid, dim3(256), 0, stream,
                     src, flow1, flow2, rfp, out);
}